// Round 1
// baseline (5666.516 us; speedup 1.0000x reference)
//
#include <hip/hip_runtime.h>

#define N_NODES 50000
#define N_EDGES 800000
#define DIM 128
#define LAYERS 4

#define GROWS 32          // rows per GEMM block
#define GKS   64          // k-slice per phase
#define XS_STRIDE 36      // GROWS+4, keeps 16B alignment, reduces store bank conflict

// hidden = temp[0] * x
__global__ __launch_bounds__(256) void init_kernel(const float4* __restrict__ x,
                                                   float4* __restrict__ hidden,
                                                   const float* __restrict__ temp, int n4) {
    int i = blockIdx.x * 256 + threadIdx.x;
    if (i >= n4) return;
    float t = temp[0];
    float4 v = x[i];
    hidden[i] = make_float4(v.x * t, v.y * t, v.z * t, v.w * t);
}

// h = x @ W + b   (x: [nrows,128], W: [128,128], b: [128])
__global__ __launch_bounds__(256) void gemm_kernel(const float* __restrict__ x,
                                                   const float* __restrict__ Wl,
                                                   const float* __restrict__ bl,
                                                   float* __restrict__ h, int nrows) {
    __shared__ float Ws[GKS][DIM];         // 32 KB, [k][col]
    __shared__ float xs[GKS][XS_STRIDE];   // ~9 KB, [k][row] transposed

    int tid  = threadIdx.x;
    int row0 = blockIdx.x * GROWS;
    int c0 = (tid & 31) * 4;   // 4 output cols per thread
    int r0 = (tid >> 5) * 4;   // 4 output rows per thread

    float acc[4][4] = {{0.f}};

    for (int p = 0; p < 2; ++p) {
        int kbase = p * GKS;
        // stage W k-slice: GKS*DIM floats = 2048 float4
        const float4* Wg  = (const float4*)(Wl + kbase * DIM);
        float4* Ws4 = (float4*)&Ws[0][0];
        for (int i = tid; i < GKS * DIM / 4; i += 256) Ws4[i] = Wg[i];
        // stage x tile transposed: GROWS rows x GKS k
        for (int i = tid; i < GROWS * GKS / 4; i += 256) {
            int r  = i / (GKS / 4);
            int kc = i % (GKS / 4);
            int grow = row0 + r;
            float4 v = make_float4(0.f, 0.f, 0.f, 0.f);
            if (grow < nrows) v = *(const float4*)(x + (size_t)grow * DIM + kbase + kc * 4);
            xs[kc * 4 + 0][r] = v.x;
            xs[kc * 4 + 1][r] = v.y;
            xs[kc * 4 + 2][r] = v.z;
            xs[kc * 4 + 3][r] = v.w;
        }
        __syncthreads();
        #pragma unroll 8
        for (int k = 0; k < GKS; ++k) {
            float4 wv = *(const float4*)&Ws[k][c0];
            float4 xv = *(const float4*)&xs[k][r0];
            acc[0][0] += xv.x * wv.x; acc[0][1] += xv.x * wv.y; acc[0][2] += xv.x * wv.z; acc[0][3] += xv.x * wv.w;
            acc[1][0] += xv.y * wv.x; acc[1][1] += xv.y * wv.y; acc[1][2] += xv.y * wv.z; acc[1][3] += xv.y * wv.w;
            acc[2][0] += xv.z * wv.x; acc[2][1] += xv.z * wv.y; acc[2][2] += xv.z * wv.z; acc[2][3] += xv.z * wv.w;
            acc[3][0] += xv.w * wv.x; acc[3][1] += xv.w * wv.y; acc[3][2] += xv.w * wv.z; acc[3][3] += xv.w * wv.w;
        }
        __syncthreads();
    }

    float4 bv = *(const float4*)(bl + c0);
    #pragma unroll
    for (int r = 0; r < 4; ++r) {
        int grow = row0 + r0 + r;
        if (grow < nrows) {
            float4 o = make_float4(acc[r][0] + bv.x, acc[r][1] + bv.y,
                                   acc[r][2] + bv.z, acc[r][3] + bv.w);
            *(float4*)(h + (size_t)grow * DIM + c0) = o;
        }
    }
}

// x_out[dst] += w * h[src]  (atomic scatter; 32 lanes per edge, float4 each)
__global__ __launch_bounds__(256) void scatter_kernel(const float* __restrict__ h,
                                                      const float* __restrict__ w,
                                                      const int* __restrict__ src,
                                                      const int* __restrict__ dst,
                                                      float* __restrict__ xout) {
    int idx = blockIdx.x * 256 + threadIdx.x;
    int e = idx >> 5;
    if (e >= N_EDGES) return;
    int c = idx & 31;
    int s = src[e];
    int d = dst[e];
    float we = w[e];
    float4 v = ((const float4*)h)[(size_t)s * (DIM / 4) + c];
    float* out = xout + (size_t)d * DIM + c * 4;
    atomicAdd(out + 0, v.x * we);
    atomicAdd(out + 1, v.y * we);
    atomicAdd(out + 2, v.z * we);
    atomicAdd(out + 3, v.w * we);
}

// x = relu(x); hidden += temp[li] * x
__global__ __launch_bounds__(256) void post_kernel(float4* __restrict__ x,
                                                   float4* __restrict__ hidden,
                                                   const float* __restrict__ temp,
                                                   int li, int n4) {
    int i = blockIdx.x * 256 + threadIdx.x;
    if (i >= n4) return;
    float t = temp[li];
    float4 v = x[i];
    v.x = fmaxf(v.x, 0.f);
    v.y = fmaxf(v.y, 0.f);
    v.z = fmaxf(v.z, 0.f);
    v.w = fmaxf(v.w, 0.f);
    x[i] = v;
    float4 hv = hidden[i];
    hv.x += t * v.x;
    hv.y += t * v.y;
    hv.z += t * v.z;
    hv.w += t * v.w;
    hidden[i] = hv;
}

extern "C" void kernel_launch(void* const* d_in, const int* in_sizes, int n_in,
                              void* d_out, int out_size, void* d_ws, size_t ws_size,
                              hipStream_t stream) {
    const float* x    = (const float*)d_in[0];
    const float* w    = (const float*)d_in[1];
    const int*   src  = (const int*)d_in[2];
    const int*   dst  = (const int*)d_in[3];
    const float* W    = (const float*)d_in[4];
    const float* b    = (const float*)d_in[5];
    const float* temp = (const float*)d_in[6];
    float* hidden = (float*)d_out;

    float* h_buf = (float*)d_ws;                         // N*D floats
    float* x_buf = h_buf + (size_t)N_NODES * DIM;        // N*D floats

    const int n4 = N_NODES * DIM / 4;
    const size_t nbytes = (size_t)N_NODES * DIM * sizeof(float);

    init_kernel<<<(n4 + 255) / 256, 256, 0, stream>>>((const float4*)x, (float4*)hidden, temp, n4);

    for (int l = 0; l < LAYERS; ++l) {
        const float* xin = (l == 0) ? x : x_buf;
        gemm_kernel<<<(N_NODES + GROWS - 1) / GROWS, 256, 0, stream>>>(
            xin, W + (size_t)l * DIM * DIM, b + (size_t)l * DIM, h_buf, N_NODES);
        hipMemsetAsync(x_buf, 0, nbytes, stream);
        scatter_kernel<<<(N_EDGES * 32 + 255) / 256, 256, 0, stream>>>(
            h_buf, w, src, dst, x_buf);
        post_kernel<<<(n4 + 255) / 256, 256, 0, stream>>>(
            (float4*)x_buf, (float4*)hidden, temp, l + 1, n4);
    }
}

// Round 2
// 766.992 us; speedup vs baseline: 7.3880x; 7.3880x over previous
//
#include <hip/hip_runtime.h>

#define N_NODES 50000
#define N_EDGES 800000
#define DIM 128
#define LAYERS 4

#define GROWS 32          // rows per GEMM block
#define GKS   64          // k-slice per phase
#define XS_STRIDE 36

// hidden = temp[0] * x
__global__ __launch_bounds__(256) void init_kernel(const float4* __restrict__ x,
                                                   float4* __restrict__ hidden,
                                                   const float* __restrict__ temp, int n4) {
    int i = blockIdx.x * 256 + threadIdx.x;
    if (i >= n4) return;
    float t = temp[0];
    float4 v = x[i];
    hidden[i] = make_float4(v.x * t, v.y * t, v.z * t, v.w * t);
}

// ---------------- CSR build ----------------

__global__ __launch_bounds__(256) void hist_kernel(const int* __restrict__ dst,
                                                   int* __restrict__ deg) {
    int e = blockIdx.x * 256 + threadIdx.x;
    if (e >= N_EDGES) return;
    atomicAdd(&deg[dst[e]], 1);
}

// single-block exclusive scan over deg[N] -> row_start[N+1], cursor[N]
__global__ __launch_bounds__(1024) void scan_kernel(const int* __restrict__ deg,
                                                    int* __restrict__ row_start,
                                                    int* __restrict__ cursor) {
    __shared__ int sums[1024];
    const int t = threadIdx.x;
    const int CHUNK = (N_NODES + 1023) / 1024;   // 49
    int lo = t * CHUNK;
    int hi = lo + CHUNK; if (hi > N_NODES) hi = N_NODES;
    if (lo > N_NODES) lo = N_NODES;
    int s = 0;
    for (int i = lo; i < hi; ++i) s += deg[i];
    sums[t] = s;
    __syncthreads();
    // Hillis-Steele inclusive scan
    for (int off = 1; off < 1024; off <<= 1) {
        int v = sums[t];
        int u = (t >= off) ? sums[t - off] : 0;
        __syncthreads();
        sums[t] = v + u;
        __syncthreads();
    }
    int run = (t > 0) ? sums[t - 1] : 0;   // exclusive prefix of this chunk
    for (int i = lo; i < hi; ++i) {
        row_start[i] = run;
        cursor[i]    = run;
        run += deg[i];
    }
    if (t == 0) row_start[N_NODES] = sums[1023];
}

// permute edges into dst-grouped order
__global__ __launch_bounds__(256) void permute_kernel(const int* __restrict__ src,
                                                      const int* __restrict__ dst,
                                                      const float* __restrict__ w,
                                                      int* __restrict__ cursor,
                                                      int* __restrict__ edge_src,
                                                      float* __restrict__ edge_w) {
    int e = blockIdx.x * 256 + threadIdx.x;
    if (e >= N_EDGES) return;
    int d = dst[e];
    int pos = atomicAdd(&cursor[d], 1);
    edge_src[pos] = src[e];
    edge_w[pos]   = w[e];
}

// ---------------- per-layer kernels ----------------

// h = x @ W + b   (x: [nrows,128], W: [128,128], b: [128])
__global__ __launch_bounds__(256) void gemm_kernel(const float* __restrict__ x,
                                                   const float* __restrict__ Wl,
                                                   const float* __restrict__ bl,
                                                   float* __restrict__ h, int nrows) {
    __shared__ float Ws[GKS][DIM];
    __shared__ float xs[GKS][XS_STRIDE];

    int tid  = threadIdx.x;
    int row0 = blockIdx.x * GROWS;
    int c0 = (tid & 31) * 4;
    int r0 = (tid >> 5) * 4;

    float acc[4][4] = {{0.f}};

    for (int p = 0; p < 2; ++p) {
        int kbase = p * GKS;
        const float4* Wg  = (const float4*)(Wl + kbase * DIM);
        float4* Ws4 = (float4*)&Ws[0][0];
        for (int i = tid; i < GKS * DIM / 4; i += 256) Ws4[i] = Wg[i];
        for (int i = tid; i < GROWS * GKS / 4; i += 256) {
            int r  = i / (GKS / 4);
            int kc = i % (GKS / 4);
            int grow = row0 + r;
            float4 v = make_float4(0.f, 0.f, 0.f, 0.f);
            if (grow < nrows) v = *(const float4*)(x + (size_t)grow * DIM + kbase + kc * 4);
            xs[kc * 4 + 0][r] = v.x;
            xs[kc * 4 + 1][r] = v.y;
            xs[kc * 4 + 2][r] = v.z;
            xs[kc * 4 + 3][r] = v.w;
        }
        __syncthreads();
        #pragma unroll 8
        for (int k = 0; k < GKS; ++k) {
            float4 wv = *(const float4*)&Ws[k][c0];
            float4 xv = *(const float4*)&xs[k][r0];
            acc[0][0] += xv.x * wv.x; acc[0][1] += xv.x * wv.y; acc[0][2] += xv.x * wv.z; acc[0][3] += xv.x * wv.w;
            acc[1][0] += xv.y * wv.x; acc[1][1] += xv.y * wv.y; acc[1][2] += xv.y * wv.z; acc[1][3] += xv.y * wv.w;
            acc[2][0] += xv.z * wv.x; acc[2][1] += xv.z * wv.y; acc[2][2] += xv.z * wv.z; acc[2][3] += xv.z * wv.w;
            acc[3][0] += xv.w * wv.x; acc[3][1] += xv.w * wv.y; acc[3][2] += xv.w * wv.z; acc[3][3] += xv.w * wv.w;
        }
        __syncthreads();
    }

    float4 bv = *(const float4*)(bl + c0);
    #pragma unroll
    for (int r = 0; r < 4; ++r) {
        int grow = row0 + r0 + r;
        if (grow < nrows) {
            float4 o = make_float4(acc[r][0] + bv.x, acc[r][1] + bv.y,
                                   acc[r][2] + bv.z, acc[r][3] + bv.w);
            *(float4*)(h + (size_t)grow * DIM + c0) = o;
        }
    }
}

// one wave per node: x[n] = relu(sum_e w_e * h[src_e]); hidden[n] += temp_l * x[n]
__global__ __launch_bounds__(256) void gather_kernel(const float2* __restrict__ h2,
                                                     const int* __restrict__ row_start,
                                                     const int* __restrict__ edge_src,
                                                     const float* __restrict__ edge_w,
                                                     float2* __restrict__ x2,
                                                     float2* __restrict__ hidden2,
                                                     const float* __restrict__ temp,
                                                     int li) {
    int wave = (blockIdx.x * 256 + threadIdx.x) >> 6;   // one wave per node
    if (wave >= N_NODES) return;
    int lane = threadIdx.x & 63;

    int e0 = row_start[wave];
    int e1 = row_start[wave + 1];

    float2 acc = make_float2(0.f, 0.f);
    for (int e = e0; e < e1; ++e) {
        int s    = edge_src[e];    // wave-uniform -> scalar load
        float we = edge_w[e];
        float2 v = h2[(size_t)s * 64 + lane];
        acc.x += we * v.x;
        acc.y += we * v.y;
    }
    acc.x = fmaxf(acc.x, 0.f);
    acc.y = fmaxf(acc.y, 0.f);

    size_t o = (size_t)wave * 64 + lane;
    x2[o] = acc;
    float t = temp[li];
    float2 hv = hidden2[o];
    hv.x += t * acc.x;
    hv.y += t * acc.y;
    hidden2[o] = hv;
}

extern "C" void kernel_launch(void* const* d_in, const int* in_sizes, int n_in,
                              void* d_out, int out_size, void* d_ws, size_t ws_size,
                              hipStream_t stream) {
    const float* x    = (const float*)d_in[0];
    const float* w    = (const float*)d_in[1];
    const int*   src  = (const int*)d_in[2];
    const int*   dst  = (const int*)d_in[3];
    const float* W    = (const float*)d_in[4];
    const float* b    = (const float*)d_in[5];
    const float* temp = (const float*)d_in[6];
    float* hidden = (float*)d_out;

    char* ws = (char*)d_ws;
    float* h_buf     = (float*)ws;                    ws += (size_t)N_NODES * DIM * sizeof(float);
    float* x_buf     = (float*)ws;                    ws += (size_t)N_NODES * DIM * sizeof(float);
    int*   deg       = (int*)ws;                      ws += (size_t)N_NODES * sizeof(int);
    int*   row_start = (int*)ws;                      ws += (size_t)(N_NODES + 1) * sizeof(int);
    int*   cursor    = (int*)ws;                      ws += (size_t)N_NODES * sizeof(int);
    int*   edge_src  = (int*)ws;                      ws += (size_t)N_EDGES * sizeof(int);
    float* edge_w    = (float*)ws;                    ws += (size_t)N_EDGES * sizeof(float);

    const int n4 = N_NODES * DIM / 4;

    // --- CSR build (every call; inputs are restored before each timed launch) ---
    hipMemsetAsync(deg, 0, (size_t)N_NODES * sizeof(int), stream);
    hist_kernel<<<(N_EDGES + 255) / 256, 256, 0, stream>>>(dst, deg);
    scan_kernel<<<1, 1024, 0, stream>>>(deg, row_start, cursor);
    permute_kernel<<<(N_EDGES + 255) / 256, 256, 0, stream>>>(src, dst, w, cursor, edge_src, edge_w);

    init_kernel<<<(n4 + 255) / 256, 256, 0, stream>>>((const float4*)x, (float4*)hidden, temp, n4);

    for (int l = 0; l < LAYERS; ++l) {
        const float* xin = (l == 0) ? x : x_buf;
        gemm_kernel<<<(N_NODES + GROWS - 1) / GROWS, 256, 0, stream>>>(
            xin, W + (size_t)l * DIM * DIM, b + (size_t)l * DIM, h_buf, N_NODES);
        gather_kernel<<<(N_NODES * 64 + 255) / 256, 256, 0, stream>>>(
            (const float2*)h_buf, row_start, edge_src, edge_w,
            (float2*)x_buf, (float2*)hidden, temp, l + 1);
    }
}

// Round 3
// 667.797 us; speedup vs baseline: 8.4854x; 1.1485x over previous
//
#include <hip/hip_runtime.h>

#define N_NODES 50000
#define N_EDGES 800000
#define DIM 128
#define LAYERS 4

#define GROWS 32          // rows per GEMM block
#define GKS   64          // k-slice per phase
#define XS_STRIDE 36

#define SCAN_BLOCK 256
#define NSCAN_BLOCKS ((N_NODES + SCAN_BLOCK - 1) / SCAN_BLOCK)   // 196

// hidden = temp[0] * x
__global__ __launch_bounds__(256) void init_kernel(const float4* __restrict__ x,
                                                   float4* __restrict__ hidden,
                                                   const float* __restrict__ temp, int n4) {
    int i = blockIdx.x * 256 + threadIdx.x;
    if (i >= n4) return;
    float t = temp[0];
    float4 v = x[i];
    hidden[i] = make_float4(v.x * t, v.y * t, v.z * t, v.w * t);
}

// ---------------- CSR build ----------------

__global__ __launch_bounds__(256) void hist_kernel(const int* __restrict__ dst,
                                                   int* __restrict__ deg) {
    int e = blockIdx.x * 256 + threadIdx.x;
    if (e >= N_EDGES) return;
    atomicAdd(&deg[dst[e]], 1);
}

// pass 1: per-block sums of deg
__global__ __launch_bounds__(256) void block_sum_kernel(const int* __restrict__ deg,
                                                        int* __restrict__ block_sums) {
    __shared__ int wsum[4];
    int i = blockIdx.x * SCAN_BLOCK + threadIdx.x;
    int v = (i < N_NODES) ? deg[i] : 0;
    // wave reduce
    #pragma unroll
    for (int off = 32; off > 0; off >>= 1) v += __shfl_down(v, off, 64);
    int lane = threadIdx.x & 63;
    int wid  = threadIdx.x >> 6;
    if (lane == 0) wsum[wid] = v;
    __syncthreads();
    if (threadIdx.x == 0)
        block_sums[blockIdx.x] = wsum[0] + wsum[1] + wsum[2] + wsum[3];
}

// pass 2: single block exclusive-scans the block sums; writes row_start[N]=total
__global__ __launch_bounds__(256) void scan_blocks_kernel(int* __restrict__ block_sums,
                                                          int* __restrict__ block_off,
                                                          int* __restrict__ row_start) {
    __shared__ int s[SCAN_BLOCK];
    int t = threadIdx.x;
    int v = (t < NSCAN_BLOCKS) ? block_sums[t] : 0;
    s[t] = v;
    __syncthreads();
    for (int off = 1; off < SCAN_BLOCK; off <<= 1) {
        int a = s[t];
        int u = (t >= off) ? s[t - off] : 0;
        __syncthreads();
        s[t] = a + u;
        __syncthreads();
    }
    if (t < NSCAN_BLOCKS) block_off[t] = s[t] - v;   // exclusive
    if (t == 0) row_start[N_NODES] = s[NSCAN_BLOCKS - 1];
}

// pass 3: block-local exclusive scan + block offset -> row_start, cursor
__global__ __launch_bounds__(256) void local_scan_kernel(const int* __restrict__ deg,
                                                         const int* __restrict__ block_off,
                                                         int* __restrict__ row_start,
                                                         int* __restrict__ cursor) {
    __shared__ int wsum[4];
    int i = blockIdx.x * SCAN_BLOCK + threadIdx.x;
    int v = (i < N_NODES) ? deg[i] : 0;
    int lane = threadIdx.x & 63;
    int wid  = threadIdx.x >> 6;
    // wave inclusive scan
    int inc = v;
    #pragma unroll
    for (int off = 1; off < 64; off <<= 1) {
        int u = __shfl_up(inc, off, 64);
        if (lane >= off) inc += u;
    }
    if (lane == 63) wsum[wid] = inc;
    __syncthreads();
    int wadd = 0;
    #pragma unroll
    for (int k = 0; k < 4; ++k) if (k < wid) wadd += wsum[k];
    int excl = block_off[blockIdx.x] + wadd + inc - v;
    if (i < N_NODES) {
        row_start[i] = excl;
        cursor[i]    = excl;
    }
}

// permute edges into dst-grouped order
__global__ __launch_bounds__(256) void permute_kernel(const int* __restrict__ src,
                                                      const int* __restrict__ dst,
                                                      const float* __restrict__ w,
                                                      int* __restrict__ cursor,
                                                      int* __restrict__ edge_src,
                                                      float* __restrict__ edge_w) {
    int e = blockIdx.x * 256 + threadIdx.x;
    if (e >= N_EDGES) return;
    int d = dst[e];
    int pos = atomicAdd(&cursor[d], 1);
    edge_src[pos] = src[e];
    edge_w[pos]   = w[e];
}

// ---------------- per-layer kernels ----------------

// h = x @ W + b   (x: [nrows,128], W: [128,128], b: [128])
__global__ __launch_bounds__(256) void gemm_kernel(const float* __restrict__ x,
                                                   const float* __restrict__ Wl,
                                                   const float* __restrict__ bl,
                                                   float* __restrict__ h, int nrows) {
    __shared__ float Ws[GKS][DIM];
    __shared__ float xs[GKS][XS_STRIDE];

    int tid  = threadIdx.x;
    int row0 = blockIdx.x * GROWS;
    int c0 = (tid & 31) * 4;
    int r0 = (tid >> 5) * 4;

    float acc[4][4] = {{0.f}};

    for (int p = 0; p < 2; ++p) {
        int kbase = p * GKS;
        const float4* Wg  = (const float4*)(Wl + kbase * DIM);
        float4* Ws4 = (float4*)&Ws[0][0];
        for (int i = tid; i < GKS * DIM / 4; i += 256) Ws4[i] = Wg[i];
        for (int i = tid; i < GROWS * GKS / 4; i += 256) {
            int r  = i / (GKS / 4);
            int kc = i % (GKS / 4);
            int grow = row0 + r;
            float4 v = make_float4(0.f, 0.f, 0.f, 0.f);
            if (grow < nrows) v = *(const float4*)(x + (size_t)grow * DIM + kbase + kc * 4);
            xs[kc * 4 + 0][r] = v.x;
            xs[kc * 4 + 1][r] = v.y;
            xs[kc * 4 + 2][r] = v.z;
            xs[kc * 4 + 3][r] = v.w;
        }
        __syncthreads();
        #pragma unroll 8
        for (int k = 0; k < GKS; ++k) {
            float4 wv = *(const float4*)&Ws[k][c0];
            float4 xv = *(const float4*)&xs[k][r0];
            acc[0][0] += xv.x * wv.x; acc[0][1] += xv.x * wv.y; acc[0][2] += xv.x * wv.z; acc[0][3] += xv.x * wv.w;
            acc[1][0] += xv.y * wv.x; acc[1][1] += xv.y * wv.y; acc[1][2] += xv.y * wv.z; acc[1][3] += xv.y * wv.w;
            acc[2][0] += xv.z * wv.x; acc[2][1] += xv.z * wv.y; acc[2][2] += xv.z * wv.z; acc[2][3] += xv.z * wv.w;
            acc[3][0] += xv.w * wv.x; acc[3][1] += xv.w * wv.y; acc[3][2] += xv.w * wv.z; acc[3][3] += xv.w * wv.w;
        }
        __syncthreads();
    }

    float4 bv = *(const float4*)(bl + c0);
    #pragma unroll
    for (int r = 0; r < 4; ++r) {
        int grow = row0 + r0 + r;
        if (grow < nrows) {
            float4 o = make_float4(acc[r][0] + bv.x, acc[r][1] + bv.y,
                                   acc[r][2] + bv.z, acc[r][3] + bv.w);
            *(float4*)(h + (size_t)grow * DIM + c0) = o;
        }
    }
}

// one wave per node: x[n] = relu(sum_e w_e * h[src_e]); hidden[n] += temp_l * x[n]
__global__ __launch_bounds__(256) void gather_kernel(const float2* __restrict__ h2,
                                                     const int* __restrict__ row_start,
                                                     const int* __restrict__ edge_src,
                                                     const float* __restrict__ edge_w,
                                                     float2* __restrict__ x2,
                                                     float2* __restrict__ hidden2,
                                                     const float* __restrict__ temp,
                                                     int li) {
    int wave = (blockIdx.x * 256 + threadIdx.x) >> 6;   // one wave per node
    if (wave >= N_NODES) return;
    int lane = threadIdx.x & 63;

    int e0 = row_start[wave];
    int e1 = row_start[wave + 1];

    float2 acc = make_float2(0.f, 0.f);
    for (int e = e0; e < e1; ++e) {
        int s    = edge_src[e];    // wave-uniform -> scalar load
        float we = edge_w[e];
        float2 v = h2[(size_t)s * 64 + lane];
        acc.x += we * v.x;
        acc.y += we * v.y;
    }
    acc.x = fmaxf(acc.x, 0.f);
    acc.y = fmaxf(acc.y, 0.f);

    size_t o = (size_t)wave * 64 + lane;
    x2[o] = acc;
    float t = temp[li];
    float2 hv = hidden2[o];
    hv.x += t * acc.x;
    hv.y += t * acc.y;
    hidden2[o] = hv;
}

extern "C" void kernel_launch(void* const* d_in, const int* in_sizes, int n_in,
                              void* d_out, int out_size, void* d_ws, size_t ws_size,
                              hipStream_t stream) {
    const float* x    = (const float*)d_in[0];
    const float* w    = (const float*)d_in[1];
    const int*   src  = (const int*)d_in[2];
    const int*   dst  = (const int*)d_in[3];
    const float* W    = (const float*)d_in[4];
    const float* b    = (const float*)d_in[5];
    const float* temp = (const float*)d_in[6];
    float* hidden = (float*)d_out;

    char* ws = (char*)d_ws;
    float* h_buf      = (float*)ws;                   ws += (size_t)N_NODES * DIM * sizeof(float);
    float* x_buf      = (float*)ws;                   ws += (size_t)N_NODES * DIM * sizeof(float);
    int*   deg        = (int*)ws;                     ws += (size_t)N_NODES * sizeof(int);
    int*   row_start  = (int*)ws;                     ws += (size_t)(N_NODES + 1) * sizeof(int);
    int*   cursor     = (int*)ws;                     ws += (size_t)N_NODES * sizeof(int);
    int*   edge_src   = (int*)ws;                     ws += (size_t)N_EDGES * sizeof(int);
    float* edge_w     = (float*)ws;                   ws += (size_t)N_EDGES * sizeof(float);
    int*   block_sums = (int*)ws;                     ws += (size_t)NSCAN_BLOCKS * sizeof(int);
    int*   block_off  = (int*)ws;                     ws += (size_t)NSCAN_BLOCKS * sizeof(int);

    const int n4 = N_NODES * DIM / 4;

    // --- CSR build (every call; inputs restored before each timed launch) ---
    hipMemsetAsync(deg, 0, (size_t)N_NODES * sizeof(int), stream);
    hist_kernel<<<(N_EDGES + 255) / 256, 256, 0, stream>>>(dst, deg);
    block_sum_kernel<<<NSCAN_BLOCKS, 256, 0, stream>>>(deg, block_sums);
    scan_blocks_kernel<<<1, 256, 0, stream>>>(block_sums, block_off, row_start);
    local_scan_kernel<<<NSCAN_BLOCKS, 256, 0, stream>>>(deg, block_off, row_start, cursor);
    permute_kernel<<<(N_EDGES + 255) / 256, 256, 0, stream>>>(src, dst, w, cursor, edge_src, edge_w);

    init_kernel<<<(n4 + 255) / 256, 256, 0, stream>>>((const float4*)x, (float4*)hidden, temp, n4);

    for (int l = 0; l < LAYERS; ++l) {
        const float* xin = (l == 0) ? x : x_buf;
        gemm_kernel<<<(N_NODES + GROWS - 1) / GROWS, 256, 0, stream>>>(
            xin, W + (size_t)l * DIM * DIM, b + (size_t)l * DIM, h_buf, N_NODES);
        gather_kernel<<<(N_NODES * 64 + 255) / 256, 256, 0, stream>>>(
            (const float2*)h_buf, row_start, edge_src, edge_w,
            (float2*)x_buf, (float2*)hidden, temp, l + 1);
    }
}

// Round 4
// 468.552 us; speedup vs baseline: 12.0937x; 1.4252x over previous
//
#include <hip/hip_runtime.h>
#include <hip/hip_fp16.h>

#define N_NODES 50000
#define N_EDGES 800000
#define DIM 128
#define LAYERS 4

#define GROWS 32          // rows per GEMM block
#define GKS   64          // k-slice per phase
#define XS_STRIDE 36

#define SCAN_BLOCK 256
#define NSCAN_BLOCKS ((N_NODES + SCAN_BLOCK - 1) / SCAN_BLOCK)   // 196

// hidden = temp[0] * x
__global__ __launch_bounds__(256) void init_kernel(const float4* __restrict__ x,
                                                   float4* __restrict__ hidden,
                                                   const float* __restrict__ temp, int n4) {
    int i = blockIdx.x * 256 + threadIdx.x;
    if (i >= n4) return;
    float t = temp[0];
    float4 v = x[i];
    hidden[i] = make_float4(v.x * t, v.y * t, v.z * t, v.w * t);
}

// ---------------- CSR build ----------------

__global__ __launch_bounds__(256) void hist_kernel(const int* __restrict__ dst,
                                                   int* __restrict__ deg) {
    int e = blockIdx.x * 256 + threadIdx.x;
    if (e >= N_EDGES) return;
    atomicAdd(&deg[dst[e]], 1);
}

__global__ __launch_bounds__(256) void block_sum_kernel(const int* __restrict__ deg,
                                                        int* __restrict__ block_sums) {
    __shared__ int wsum[4];
    int i = blockIdx.x * SCAN_BLOCK + threadIdx.x;
    int v = (i < N_NODES) ? deg[i] : 0;
    #pragma unroll
    for (int off = 32; off > 0; off >>= 1) v += __shfl_down(v, off, 64);
    int lane = threadIdx.x & 63;
    int wid  = threadIdx.x >> 6;
    if (lane == 0) wsum[wid] = v;
    __syncthreads();
    if (threadIdx.x == 0)
        block_sums[blockIdx.x] = wsum[0] + wsum[1] + wsum[2] + wsum[3];
}

__global__ __launch_bounds__(256) void scan_blocks_kernel(int* __restrict__ block_sums,
                                                          int* __restrict__ block_off,
                                                          int* __restrict__ row_start) {
    __shared__ int s[SCAN_BLOCK];
    int t = threadIdx.x;
    int v = (t < NSCAN_BLOCKS) ? block_sums[t] : 0;
    s[t] = v;
    __syncthreads();
    for (int off = 1; off < SCAN_BLOCK; off <<= 1) {
        int a = s[t];
        int u = (t >= off) ? s[t - off] : 0;
        __syncthreads();
        s[t] = a + u;
        __syncthreads();
    }
    if (t < NSCAN_BLOCKS) block_off[t] = s[t] - v;
    if (t == 0) row_start[N_NODES] = s[NSCAN_BLOCKS - 1];
}

__global__ __launch_bounds__(256) void local_scan_kernel(const int* __restrict__ deg,
                                                         const int* __restrict__ block_off,
                                                         int* __restrict__ row_start,
                                                         int* __restrict__ cursor) {
    __shared__ int wsum[4];
    int i = blockIdx.x * SCAN_BLOCK + threadIdx.x;
    int v = (i < N_NODES) ? deg[i] : 0;
    int lane = threadIdx.x & 63;
    int wid  = threadIdx.x >> 6;
    int inc = v;
    #pragma unroll
    for (int off = 1; off < 64; off <<= 1) {
        int u = __shfl_up(inc, off, 64);
        if (lane >= off) inc += u;
    }
    if (lane == 63) wsum[wid] = inc;
    __syncthreads();
    int wadd = 0;
    #pragma unroll
    for (int k = 0; k < 4; ++k) if (k < wid) wadd += wsum[k];
    int excl = block_off[blockIdx.x] + wadd + inc - v;
    if (i < N_NODES) {
        row_start[i] = excl;
        cursor[i]    = excl;
    }
}

__global__ __launch_bounds__(256) void permute_kernel(const int* __restrict__ src,
                                                      const int* __restrict__ dst,
                                                      const float* __restrict__ w,
                                                      int* __restrict__ cursor,
                                                      int* __restrict__ edge_src,
                                                      float* __restrict__ edge_w) {
    int e = blockIdx.x * 256 + threadIdx.x;
    if (e >= N_EDGES) return;
    int d = dst[e];
    int pos = atomicAdd(&cursor[d], 1);
    edge_src[pos] = src[e];
    edge_w[pos]   = w[e];
}

// ---------------- per-layer kernels ----------------

// h = fp16(x @ W + b)
__global__ __launch_bounds__(256) void gemm_kernel(const float* __restrict__ x,
                                                   const float* __restrict__ Wl,
                                                   const float* __restrict__ bl,
                                                   __half* __restrict__ h, int nrows) {
    __shared__ float Ws[GKS][DIM];
    __shared__ float xs[GKS][XS_STRIDE];

    int tid  = threadIdx.x;
    int row0 = blockIdx.x * GROWS;
    int c0 = (tid & 31) * 4;
    int r0 = (tid >> 5) * 4;

    float acc[4][4] = {{0.f}};

    for (int p = 0; p < 2; ++p) {
        int kbase = p * GKS;
        const float4* Wg  = (const float4*)(Wl + kbase * DIM);
        float4* Ws4 = (float4*)&Ws[0][0];
        for (int i = tid; i < GKS * DIM / 4; i += 256) Ws4[i] = Wg[i];
        for (int i = tid; i < GROWS * GKS / 4; i += 256) {
            int r  = i / (GKS / 4);
            int kc = i % (GKS / 4);
            int grow = row0 + r;
            float4 v = make_float4(0.f, 0.f, 0.f, 0.f);
            if (grow < nrows) v = *(const float4*)(x + (size_t)grow * DIM + kbase + kc * 4);
            xs[kc * 4 + 0][r] = v.x;
            xs[kc * 4 + 1][r] = v.y;
            xs[kc * 4 + 2][r] = v.z;
            xs[kc * 4 + 3][r] = v.w;
        }
        __syncthreads();
        #pragma unroll 8
        for (int k = 0; k < GKS; ++k) {
            float4 wv = *(const float4*)&Ws[k][c0];
            float4 xv = *(const float4*)&xs[k][r0];
            acc[0][0] += xv.x * wv.x; acc[0][1] += xv.x * wv.y; acc[0][2] += xv.x * wv.z; acc[0][3] += xv.x * wv.w;
            acc[1][0] += xv.y * wv.x; acc[1][1] += xv.y * wv.y; acc[1][2] += xv.y * wv.z; acc[1][3] += xv.y * wv.w;
            acc[2][0] += xv.z * wv.x; acc[2][1] += xv.z * wv.y; acc[2][2] += xv.z * wv.z; acc[2][3] += xv.z * wv.w;
            acc[3][0] += xv.w * wv.x; acc[3][1] += xv.w * wv.y; acc[3][2] += xv.w * wv.z; acc[3][3] += xv.w * wv.w;
        }
        __syncthreads();
    }

    float4 bv = *(const float4*)(bl + c0);
    #pragma unroll
    for (int r = 0; r < 4; ++r) {
        int grow = row0 + r0 + r;
        if (grow < nrows) {
            union { __half2 hh[2]; float2 f2; } u;
            u.hh[0] = __floats2half2_rn(acc[r][0] + bv.x, acc[r][1] + bv.y);
            u.hh[1] = __floats2half2_rn(acc[r][2] + bv.z, acc[r][3] + bv.w);
            *(float2*)(h + (size_t)grow * DIM + c0) = u.f2;
        }
    }
}

// one wave per node: x[n] = relu(sum_e w_e * h[src_e]); hidden[n] += temp_l * x[n]
// edge meta staged across lanes (one coalesced load / 64 edges), broadcast via shfl;
// h-row gathers unrolled x4 for loads-in-flight.
__global__ __launch_bounds__(256) void gather_kernel(const __half2* __restrict__ h2,
                                                     const int* __restrict__ row_start,
                                                     const int* __restrict__ edge_src,
                                                     const float* __restrict__ edge_w,
                                                     float2* __restrict__ x2,
                                                     float2* __restrict__ hidden2,
                                                     const float* __restrict__ temp,
                                                     int li) {
    int node = (blockIdx.x * 256 + threadIdx.x) >> 6;   // one wave per node
    if (node >= N_NODES) return;
    int lane = threadIdx.x & 63;

    int e0 = row_start[node];
    int e1 = row_start[node + 1];

    float2 acc = make_float2(0.f, 0.f);

    for (int base = e0; base < e1; base += 64) {
        int my_e = base + lane;
        int ms = 0; float mw = 0.f;
        if (my_e < e1) { ms = edge_src[my_e]; mw = edge_w[my_e]; }
        int cnt = e1 - base; if (cnt > 64) cnt = 64;

        int j = 0;
        for (; j + 4 <= cnt; j += 4) {
            int   s0 = __shfl(ms, j,     64), s1 = __shfl(ms, j + 1, 64);
            int   s2 = __shfl(ms, j + 2, 64), s3 = __shfl(ms, j + 3, 64);
            float w0 = __shfl(mw, j,     64), w1 = __shfl(mw, j + 1, 64);
            float w2 = __shfl(mw, j + 2, 64), w3 = __shfl(mw, j + 3, 64);
            __half2 v0 = h2[(size_t)s0 * 64 + lane];
            __half2 v1 = h2[(size_t)s1 * 64 + lane];
            __half2 v2 = h2[(size_t)s2 * 64 + lane];
            __half2 v3 = h2[(size_t)s3 * 64 + lane];
            float2 f0 = __half22float2(v0);
            float2 f1 = __half22float2(v1);
            float2 f2 = __half22float2(v2);
            float2 f3 = __half22float2(v3);
            acc.x += w0 * f0.x; acc.y += w0 * f0.y;
            acc.x += w1 * f1.x; acc.y += w1 * f1.y;
            acc.x += w2 * f2.x; acc.y += w2 * f2.y;
            acc.x += w3 * f3.x; acc.y += w3 * f3.y;
        }
        for (; j < cnt; ++j) {
            int   s = __shfl(ms, j, 64);
            float we = __shfl(mw, j, 64);
            float2 f = __half22float2(h2[(size_t)s * 64 + lane]);
            acc.x += we * f.x; acc.y += we * f.y;
        }
    }

    acc.x = fmaxf(acc.x, 0.f);
    acc.y = fmaxf(acc.y, 0.f);

    size_t o = (size_t)node * 64 + lane;
    x2[o] = acc;
    float t = temp[li];
    float2 hv = hidden2[o];
    hv.x += t * acc.x;
    hv.y += t * acc.y;
    hidden2[o] = hv;
}

extern "C" void kernel_launch(void* const* d_in, const int* in_sizes, int n_in,
                              void* d_out, int out_size, void* d_ws, size_t ws_size,
                              hipStream_t stream) {
    const float* x    = (const float*)d_in[0];
    const float* w    = (const float*)d_in[1];
    const int*   src  = (const int*)d_in[2];
    const int*   dst  = (const int*)d_in[3];
    const float* W    = (const float*)d_in[4];
    const float* b    = (const float*)d_in[5];
    const float* temp = (const float*)d_in[6];
    float* hidden = (float*)d_out;

    char* ws = (char*)d_ws;
    __half* h_buf     = (__half*)ws;                  ws += (size_t)N_NODES * DIM * sizeof(__half);
    float*  x_buf     = (float*)ws;                   ws += (size_t)N_NODES * DIM * sizeof(float);
    int*    deg       = (int*)ws;                     ws += (size_t)N_NODES * sizeof(int);
    int*    row_start = (int*)ws;                     ws += (size_t)(N_NODES + 1) * sizeof(int);
    int*    cursor    = (int*)ws;                     ws += (size_t)N_NODES * sizeof(int);
    int*    edge_src  = (int*)ws;                     ws += (size_t)N_EDGES * sizeof(int);
    float*  edge_w    = (float*)ws;                   ws += (size_t)N_EDGES * sizeof(float);
    int*    block_sums = (int*)ws;                    ws += (size_t)NSCAN_BLOCKS * sizeof(int);
    int*    block_off  = (int*)ws;                    ws += (size_t)NSCAN_BLOCKS * sizeof(int);

    const int n4 = N_NODES * DIM / 4;

    // --- CSR build (every call; inputs restored before each timed launch) ---
    hipMemsetAsync(deg, 0, (size_t)N_NODES * sizeof(int), stream);
    hist_kernel<<<(N_EDGES + 255) / 256, 256, 0, stream>>>(dst, deg);
    block_sum_kernel<<<NSCAN_BLOCKS, 256, 0, stream>>>(deg, block_sums);
    scan_blocks_kernel<<<1, 256, 0, stream>>>(block_sums, block_off, row_start);
    local_scan_kernel<<<NSCAN_BLOCKS, 256, 0, stream>>>(deg, block_off, row_start, cursor);
    permute_kernel<<<(N_EDGES + 255) / 256, 256, 0, stream>>>(src, dst, w, cursor, edge_src, edge_w);

    init_kernel<<<(n4 + 255) / 256, 256, 0, stream>>>((const float4*)x, (float4*)hidden, temp, n4);

    for (int l = 0; l < LAYERS; ++l) {
        const float* xin = (l == 0) ? x : x_buf;
        gemm_kernel<<<(N_NODES + GROWS - 1) / GROWS, 256, 0, stream>>>(
            xin, W + (size_t)l * DIM * DIM, b + (size_t)l * DIM, h_buf, N_NODES);
        gather_kernel<<<(N_NODES * 64 + 255) / 256, 256, 0, stream>>>(
            (const __half2*)h_buf, row_start, edge_src, edge_w,
            (float2*)x_buf, (float2*)hidden, temp, l + 1);
    }
}

// Round 5
// 414.038 us; speedup vs baseline: 13.6860x; 1.1317x over previous
//
#include <hip/hip_runtime.h>
#include <hip/hip_fp16.h>

#define N_NODES 50000
#define N_EDGES 800000
#define DIM 128
#define LAYERS 4

#define SCAN_BLOCK 256
#define NSCAN_BLOCKS ((N_NODES + SCAN_BLOCK - 1) / SCAN_BLOCK)   // 196

typedef __attribute__((ext_vector_type(8))) _Float16 half8;
typedef __attribute__((ext_vector_type(4))) float float4v;

// hidden = temp[0] * x
__global__ __launch_bounds__(256) void init_kernel(const float4* __restrict__ x,
                                                   float4* __restrict__ hidden,
                                                   const float* __restrict__ temp, int n4) {
    int i = blockIdx.x * 256 + threadIdx.x;
    if (i >= n4) return;
    float t = temp[0];
    float4 v = x[i];
    hidden[i] = make_float4(v.x * t, v.y * t, v.z * t, v.w * t);
}

// ---------------- CSR build ----------------

__global__ __launch_bounds__(256) void hist_kernel(const int* __restrict__ dst,
                                                   int* __restrict__ deg) {
    int e = blockIdx.x * 256 + threadIdx.x;
    if (e >= N_EDGES) return;
    atomicAdd(&deg[dst[e]], 1);
}

__global__ __launch_bounds__(256) void block_sum_kernel(const int* __restrict__ deg,
                                                        int* __restrict__ block_sums) {
    __shared__ int wsum[4];
    int i = blockIdx.x * SCAN_BLOCK + threadIdx.x;
    int v = (i < N_NODES) ? deg[i] : 0;
    #pragma unroll
    for (int off = 32; off > 0; off >>= 1) v += __shfl_down(v, off, 64);
    int lane = threadIdx.x & 63;
    int wid  = threadIdx.x >> 6;
    if (lane == 0) wsum[wid] = v;
    __syncthreads();
    if (threadIdx.x == 0)
        block_sums[blockIdx.x] = wsum[0] + wsum[1] + wsum[2] + wsum[3];
}

__global__ __launch_bounds__(256) void scan_blocks_kernel(int* __restrict__ block_sums,
                                                          int* __restrict__ block_off,
                                                          int* __restrict__ row_start) {
    __shared__ int s[SCAN_BLOCK];
    int t = threadIdx.x;
    int v = (t < NSCAN_BLOCKS) ? block_sums[t] : 0;
    s[t] = v;
    __syncthreads();
    for (int off = 1; off < SCAN_BLOCK; off <<= 1) {
        int a = s[t];
        int u = (t >= off) ? s[t - off] : 0;
        __syncthreads();
        s[t] = a + u;
        __syncthreads();
    }
    if (t < NSCAN_BLOCKS) block_off[t] = s[t] - v;
    if (t == 0) row_start[N_NODES] = s[NSCAN_BLOCKS - 1];
}

__global__ __launch_bounds__(256) void local_scan_kernel(const int* __restrict__ deg,
                                                         const int* __restrict__ block_off,
                                                         int* __restrict__ row_start,
                                                         int* __restrict__ cursor) {
    __shared__ int wsum[4];
    int i = blockIdx.x * SCAN_BLOCK + threadIdx.x;
    int v = (i < N_NODES) ? deg[i] : 0;
    int lane = threadIdx.x & 63;
    int wid  = threadIdx.x >> 6;
    int inc = v;
    #pragma unroll
    for (int off = 1; off < 64; off <<= 1) {
        int u = __shfl_up(inc, off, 64);
        if (lane >= off) inc += u;
    }
    if (lane == 63) wsum[wid] = inc;
    __syncthreads();
    int wadd = 0;
    #pragma unroll
    for (int k = 0; k < 4; ++k) if (k < wid) wadd += wsum[k];
    int excl = block_off[blockIdx.x] + wadd + inc - v;
    if (i < N_NODES) {
        row_start[i] = excl;
        cursor[i]    = excl;
    }
}

// permute edges into dst-grouped order; single packed 8B store per edge
__global__ __launch_bounds__(256) void permute_kernel(const int* __restrict__ src,
                                                      const int* __restrict__ dst,
                                                      const float* __restrict__ w,
                                                      int* __restrict__ cursor,
                                                      int2* __restrict__ edge_pair) {
    int e = blockIdx.x * 256 + threadIdx.x;
    if (e >= N_EDGES) return;
    int d = dst[e];
    int pos = atomicAdd(&cursor[d], 1);
    int2 p;
    p.x = src[e];
    p.y = __float_as_int(w[e]);
    edge_pair[pos] = p;
}

// ---------------- per-layer kernels ----------------

// W[l] fp32 [K][N] -> Wt fp16 [N][K], all layers in one dispatch
__global__ __launch_bounds__(256) void wt_prep_kernel(const float* __restrict__ W,
                                                      __half* __restrict__ Wt) {
    int i = blockIdx.x * 256 + threadIdx.x;
    if (i >= LAYERS * DIM * DIM) return;
    int l   = i >> 14;            // /16384
    int rem = i & 16383;
    int k = rem >> 7;
    int n = rem & 127;
    Wt[(size_t)l * DIM * DIM + n * DIM + k] = __float2half(W[(size_t)l * DIM * DIM + k * DIM + n]);
}

// h = fp16(x @ W + b) via MFMA f16. 64 rows x 128 cols per block, 4 waves.
#define AP 136   // padded LDS row (halves): stride 272B = 68 dwords = 4 banks offset/row
__global__ __launch_bounds__(256) void gemm_mfma_kernel(const float* __restrict__ x,
                                                        const __half* __restrict__ Wt,
                                                        const float* __restrict__ bl,
                                                        __half* __restrict__ h, int nrows) {
    __shared__ __half Ah[64][AP];    // 17.4 KB
    __shared__ __half Ws[DIM][AP];   // 34.8 KB
    int tid  = threadIdx.x;
    int wave = tid >> 6;
    int lane = tid & 63;
    int row0 = blockIdx.x * 64;

    // stage A: 64 rows x 128 fp32 -> fp16 (2048 float4, 8 per thread)
    for (int i = tid; i < 64 * 32; i += 256) {
        int r  = i >> 5;
        int c4 = i & 31;
        int grow = row0 + r;
        float4 v = make_float4(0.f, 0.f, 0.f, 0.f);
        if (grow < nrows) v = *(const float4*)(x + (size_t)grow * DIM + c4 * 4);
        *(__half2*)&Ah[r][c4 * 4]     = __floats2half2_rn(v.x, v.y);
        *(__half2*)&Ah[r][c4 * 4 + 2] = __floats2half2_rn(v.z, v.w);
    }
    // stage Wt: 128 rows x 128 halves, 16B chunks (2048 chunks, 8 per thread)
    for (int i = tid; i < 128 * 16; i += 256) {
        int r = i >> 4;
        int c = (i & 15) * 8;   // halves
        *(float4*)&Ws[r][c] = *(const float4*)(Wt + (size_t)r * DIM + c);
    }
    __syncthreads();

    int am  = lane & 15;
    int ak8 = (lane >> 4) * 8;
    float4v acc[4][2];
    #pragma unroll
    for (int mi = 0; mi < 4; ++mi)
        #pragma unroll
        for (int ni = 0; ni < 2; ++ni)
            acc[mi][ni] = (float4v)(0.f);

    #pragma unroll
    for (int kk = 0; kk < 4; ++kk) {
        int k0 = kk * 32 + ak8;
        half8 a[4], b[2];
        #pragma unroll
        for (int mi = 0; mi < 4; ++mi) a[mi] = *(const half8*)&Ah[mi * 16 + am][k0];
        #pragma unroll
        for (int ni = 0; ni < 2; ++ni) b[ni] = *(const half8*)&Ws[wave * 32 + ni * 16 + am][k0];
        #pragma unroll
        for (int mi = 0; mi < 4; ++mi)
            #pragma unroll
            for (int ni = 0; ni < 2; ++ni)
                acc[mi][ni] = __builtin_amdgcn_mfma_f32_16x16x32_f16(a[mi], b[ni], acc[mi][ni], 0, 0, 0);
    }

    // epilogue: C/D layout col=lane&15, row=(lane>>4)*4+reg
    int q  = lane >> 4;
    int cc = lane & 15;
    #pragma unroll
    for (int ni = 0; ni < 2; ++ni) {
        int col = wave * 32 + ni * 16 + cc;
        float bv = bl[col];
        #pragma unroll
        for (int mi = 0; mi < 4; ++mi) {
            #pragma unroll
            for (int r = 0; r < 4; ++r) {
                int grow = row0 + mi * 16 + q * 4 + r;
                if (grow < nrows)
                    h[(size_t)grow * DIM + col] = __float2half(acc[mi][ni][r] + bv);
            }
        }
    }
}

// one wave per node: x[n] = relu(sum_e w_e * h[src_e]); hidden[n] += temp_l * x[n]
__global__ __launch_bounds__(256) void gather_kernel(const __half2* __restrict__ h2,
                                                     const int* __restrict__ row_start,
                                                     const int2* __restrict__ edge_pair,
                                                     float2* __restrict__ x2,
                                                     float2* __restrict__ hidden2,
                                                     const float* __restrict__ temp,
                                                     int li) {
    int node = (blockIdx.x * 256 + threadIdx.x) >> 6;
    if (node >= N_NODES) return;
    int lane = threadIdx.x & 63;

    int e0 = row_start[node];
    int e1 = row_start[node + 1];

    float2 acc = make_float2(0.f, 0.f);

    for (int base = e0; base < e1; base += 64) {
        int my_e = base + lane;
        int ms = 0; float mw = 0.f;
        if (my_e < e1) {
            int2 p = edge_pair[my_e];
            ms = p.x;
            mw = __int_as_float(p.y);
        }
        int cnt = e1 - base; if (cnt > 64) cnt = 64;

        int j = 0;
        for (; j + 8 <= cnt; j += 8) {
            int ss[8]; float ww[8]; __half2 vv[8];
            #pragma unroll
            for (int t = 0; t < 8; ++t) {
                ss[t] = __shfl(ms, j + t, 64);
                ww[t] = __shfl(mw, j + t, 64);
            }
            #pragma unroll
            for (int t = 0; t < 8; ++t) vv[t] = h2[(size_t)ss[t] * 64 + lane];
            #pragma unroll
            for (int t = 0; t < 8; ++t) {
                float2 f = __half22float2(vv[t]);
                acc.x += ww[t] * f.x;
                acc.y += ww[t] * f.y;
            }
        }
        for (; j < cnt; ++j) {
            int   s  = __shfl(ms, j, 64);
            float we = __shfl(mw, j, 64);
            float2 f = __half22float2(h2[(size_t)s * 64 + lane]);
            acc.x += we * f.x;
            acc.y += we * f.y;
        }
    }

    acc.x = fmaxf(acc.x, 0.f);
    acc.y = fmaxf(acc.y, 0.f);

    size_t o = (size_t)node * 64 + lane;
    x2[o] = acc;
    float t = temp[li];
    float2 hv = hidden2[o];
    hv.x += t * acc.x;
    hv.y += t * acc.y;
    hidden2[o] = hv;
}

extern "C" void kernel_launch(void* const* d_in, const int* in_sizes, int n_in,
                              void* d_out, int out_size, void* d_ws, size_t ws_size,
                              hipStream_t stream) {
    const float* x    = (const float*)d_in[0];
    const float* w    = (const float*)d_in[1];
    const int*   src  = (const int*)d_in[2];
    const int*   dst  = (const int*)d_in[3];
    const float* W    = (const float*)d_in[4];
    const float* b    = (const float*)d_in[5];
    const float* temp = (const float*)d_in[6];
    float* hidden = (float*)d_out;

    char* ws = (char*)d_ws;
    __half* h_buf      = (__half*)ws;                 ws += (size_t)N_NODES * DIM * sizeof(__half);
    float*  x_buf      = (float*)ws;                  ws += (size_t)N_NODES * DIM * sizeof(float);
    __half* Wt         = (__half*)ws;                 ws += (size_t)LAYERS * DIM * DIM * sizeof(__half);
    int*    deg        = (int*)ws;                    ws += (size_t)N_NODES * sizeof(int);
    int*    row_start  = (int*)ws;                    ws += (size_t)(N_NODES + 1) * sizeof(int);
    int*    cursor     = (int*)ws;                    ws += (size_t)N_NODES * sizeof(int);
    int2*   edge_pair  = (int2*)ws;                   ws += (size_t)N_EDGES * sizeof(int2);
    int*    block_sums = (int*)ws;                    ws += (size_t)NSCAN_BLOCKS * sizeof(int);
    int*    block_off  = (int*)ws;                    ws += (size_t)NSCAN_BLOCKS * sizeof(int);

    const int n4 = N_NODES * DIM / 4;

    // --- CSR build + weight prep (every call) ---
    hipMemsetAsync(deg, 0, (size_t)N_NODES * sizeof(int), stream);
    hist_kernel<<<(N_EDGES + 255) / 256, 256, 0, stream>>>(dst, deg);
    block_sum_kernel<<<NSCAN_BLOCKS, 256, 0, stream>>>(deg, block_sums);
    scan_blocks_kernel<<<1, 256, 0, stream>>>(block_sums, block_off, row_start);
    local_scan_kernel<<<NSCAN_BLOCKS, 256, 0, stream>>>(deg, block_off, row_start, cursor);
    permute_kernel<<<(N_EDGES + 255) / 256, 256, 0, stream>>>(src, dst, w, cursor, edge_pair);
    wt_prep_kernel<<<(LAYERS * DIM * DIM + 255) / 256, 256, 0, stream>>>(W, Wt);

    init_kernel<<<(n4 + 255) / 256, 256, 0, stream>>>((const float4*)x, (float4*)hidden, temp, n4);

    for (int l = 0; l < LAYERS; ++l) {
        const float* xin = (l == 0) ? x : x_buf;
        gemm_mfma_kernel<<<(N_NODES + 63) / 64, 256, 0, stream>>>(
            xin, Wt + (size_t)l * DIM * DIM, b + (size_t)l * DIM, h_buf, N_NODES);
        gather_kernel<<<(N_NODES * 64 + 255) / 256, 256, 0, stream>>>(
            (const __half2*)h_buf, row_start, edge_pair,
            (float2*)x_buf, (float2*)hidden, temp, l + 1);
    }
}